// Round 1
// baseline (51.111 us; speedup 1.0000x reference)
//
#include <hip/hip_runtime.h>

// Gather rows from kv_buffer at loc, split into nope (512) + rope (64) slices.
// Sizes fixed by the reference.
#define NUM_SLOTS 262144
#define BUF_DIM   576
#define NOPE_DIM  512
#define ROPE_DIM  64
#define N_LOC     65536

// One 64-lane wave per gathered row. Row = 576 floats = 144 float4.
//   nope slice: float4[0..127]  -> 2 full-wave float4 iterations
//   rope slice: float4[128..143]-> lanes 0..15
// All bases are 16B-aligned (576*4 = 2304 B, 512*4 = 2048 B, 64*4 = 256 B).
__global__ __launch_bounds__(256) void gather_split_kernel(
    const float* __restrict__ kv,
    const int*   __restrict__ loc,
    float*       __restrict__ out_nope,
    float*       __restrict__ out_rope)
{
    const int row  = (blockIdx.x << 2) + (threadIdx.x >> 6);  // 4 waves/block
    const int lane = threadIdx.x & 63;
    if (row >= N_LOC) return;

    const long long src = (long long)loc[row];
    const float4* __restrict__ s4 =
        reinterpret_cast<const float4*>(kv + src * (long long)BUF_DIM);
    float4* __restrict__ dn =
        reinterpret_cast<float4*>(out_nope + (long long)row * NOPE_DIM);
    float4* __restrict__ dr =
        reinterpret_cast<float4*>(out_rope + (long long)row * ROPE_DIM);

    // nope: 128 float4 per row
    float4 a = s4[lane];
    float4 b = s4[lane + 64];
    dn[lane]      = a;
    dn[lane + 64] = b;
    // rope: 16 float4 per row
    if (lane < 16) {
        dr[lane] = s4[128 + lane];
    }
}

extern "C" void kernel_launch(void* const* d_in, const int* in_sizes, int n_in,
                              void* d_out, int out_size, void* d_ws, size_t ws_size,
                              hipStream_t stream) {
    const float* kv  = (const float*)d_in[0];
    const int*   loc = (const int*)d_in[1];
    // d_out = [k_nope (N_LOC*NOPE_DIM) | k_rope (N_LOC*ROPE_DIM)] flat f32
    float* out_nope = (float*)d_out;
    float* out_rope = (float*)d_out + (long long)N_LOC * NOPE_DIM;

    dim3 block(256);
    dim3 grid(N_LOC / 4);  // 4 rows per block
    gather_split_kernel<<<grid, block, 0, stream>>>(kv, loc, out_nope, out_rope);
}

// Round 3
// 49.051 us; speedup vs baseline: 1.0420x; 1.0420x over previous
//
#include <hip/hip_runtime.h>

// Gather rows from kv_buffer at loc, split into nope (512) + rope (64) slices.
#define NUM_SLOTS 262144
#define BUF_DIM   576
#define NOPE_DIM  512
#define ROPE_DIM  64
#define N_LOC     65536

// Native 16B vector type: __builtin_nontemporal_store requires a clang
// ext_vector, not HIP's float4 class.
typedef float f32x4 __attribute__((ext_vector_type(4)));

// One 64-lane wave per gathered row. Row = 576 floats = 144 float4.
//   nope slice: float4[0..127]  -> 2 full-wave float4 iterations
//   rope slice: float4[128..143]-> lanes 0..15
// Stores are non-temporal: outputs are streaming/never re-read; keeping them
// out of L2/L3 leaves cache capacity for duplicated gather rows (~11.5% of
// loc entries are repeats).
__global__ __launch_bounds__(256) void gather_split_kernel(
    const float* __restrict__ kv,
    const int*   __restrict__ loc,
    float*       __restrict__ out_nope,
    float*       __restrict__ out_rope)
{
    const int row  = (blockIdx.x << 2) + (threadIdx.x >> 6);  // 4 waves/block
    const int lane = threadIdx.x & 63;
    if (row >= N_LOC) return;

    const long long src = (long long)loc[row];
    const f32x4* __restrict__ s4 =
        reinterpret_cast<const f32x4*>(kv + src * (long long)BUF_DIM);
    f32x4* __restrict__ dn =
        reinterpret_cast<f32x4*>(out_nope + (long long)row * NOPE_DIM);
    f32x4* __restrict__ dr =
        reinterpret_cast<f32x4*>(out_rope + (long long)row * ROPE_DIM);

    // nope: 128 float4 per row
    f32x4 a = s4[lane];
    f32x4 b = s4[lane + 64];
    __builtin_nontemporal_store(a, &dn[lane]);
    __builtin_nontemporal_store(b, &dn[lane + 64]);
    // rope: 16 float4 per row
    if (lane < 16) {
        f32x4 c = s4[128 + lane];
        __builtin_nontemporal_store(c, &dr[lane]);
    }
}

extern "C" void kernel_launch(void* const* d_in, const int* in_sizes, int n_in,
                              void* d_out, int out_size, void* d_ws, size_t ws_size,
                              hipStream_t stream) {
    const float* kv  = (const float*)d_in[0];
    const int*   loc = (const int*)d_in[1];
    // d_out = [k_nope (N_LOC*NOPE_DIM) | k_rope (N_LOC*ROPE_DIM)] flat f32
    float* out_nope = (float*)d_out;
    float* out_rope = (float*)d_out + (long long)N_LOC * NOPE_DIM;

    dim3 block(256);
    dim3 grid(N_LOC / 4);  // 4 rows per block
    gather_split_kernel<<<grid, block, 0, stream>>>(kv, loc, out_nope, out_rope);
}